// Round 13
// baseline (175.422 us; speedup 1.0000x reference)
//
#include <hip/hip_runtime.h>
#include <hip/hip_fp16.h>

#define D 48
#define DP 64             // padded gather-row stride in halfs (128 B = 1 line)
#define KORD 4
#define RSH 7             // 128 dst ids per bucket
#define RNG 128
#define NBK 391           // ceil(50000/128)
#define HB 64             // histogram chunks
#define HHALF 25000       // node ids per half
#define HW 12500          // packed words per half
#define S1CH 6272         // pass-1 chunk capacity (>= ceil(E/256))
#define MAXB 6144         // max PADDED entries per bucket
#define PADB 960          // per-bucket slack for 8-rounding (multiple of 8)

// ---- outdeg histogram (privatized, no global atomics) + coarse bucket hist ----
__global__ __launch_bounds__(1024) void k_hist(const int* __restrict__ row,
        const int* __restrict__ col, uint* __restrict__ histbuf,
        uint* __restrict__ coarse, int E, int chunk) {
    __shared__ uint hist[HW];     // 50 KB: packed ushort counters for one id-half
    __shared__ uint ch[NBK];
    int k = blockIdx.x >> 1, h = blockIdx.x & 1;
    int tid = threadIdx.x;
    for (int i = tid; i < HW; i += 1024) hist[i] = 0;
    if (h == 0) for (int i = tid; i < NBK; i += 1024) ch[i] = 0;
    __syncthreads();
    int lo = h * HHALF;
    int s = k * chunk, e = min(E, s + chunk);
    for (int i = s + tid; i < e; i += 1024) {
        int r = row[i], c = col[i];
        if (r != c) {
            unsigned rl = (unsigned)(r - lo);
            if (rl < HHALF) atomicAdd(&hist[rl >> 1], 1u << ((rl & 1) * 16));
            if (h == 0) atomicAdd(&ch[c >> RSH], 1u);
        }
    }
    __syncthreads();
    uint* dst = histbuf + (size_t)k * (2 * HW) + (size_t)h * HW;
    for (int i = tid; i < HW; i += 1024) dst[i] = hist[i];
    if (h == 0) for (int i = tid; i < NBK; i += 1024) atomicAdd(&coarse[i], ch[i]);
}

// ---- reduce private histograms -> dis = deg^{-1/2}; block 0 also scans coarse ----
__global__ void k_reduce(const uint* __restrict__ histbuf, float* __restrict__ dis,
                         int nwords, const uint* __restrict__ coarse,
                         int* __restrict__ base, int* __restrict__ cursor, int nbk) {
    int t = blockIdx.x * blockDim.x + threadIdx.x;  // word t = nodes 2t,2t+1
    if (t < nwords) {
        uint lo = 0, hi = 0;
#pragma unroll 8
        for (int k = 0; k < HB; ++k) {
            uint w = histbuf[(size_t)k * (2 * HW) + t];
            lo += w & 0xFFFFu;
            hi += w >> 16;
        }
        float2 d;
        d.x = lo ? rsqrtf((float)lo) : 0.0f;
        d.y = hi ? rsqrtf((float)hi) : 0.0f;
        *(float2*)(dis + 2 * t) = d;
    }
    // fold-in of the coarse-bucket exclusive scan (independent data)
    if (blockIdx.x == 0 && threadIdx.x < 64) {
        int lane = threadIdx.x;
        int carry = 0;
        for (int s = 0; s < nbk; s += 64) {
            int i = s + lane;
            int v = (i < nbk) ? (int)coarse[i] : 0;
            int incl = v;
#pragma unroll
            for (int off = 1; off < 64; off <<= 1) {
                int tt = __shfl_up(incl, off);
                if (lane >= off) incl += tt;
            }
            if (i < nbk) { int ex = carry + incl - v; base[i] = ex; cursor[i] = ex; }
            carry += __shfl(incl, 63);
        }
        if (lane == 0) base[nbk] = carry;
    }
}

// ---- pass 1: scatter edges into coarse buckets, coalesced run writes ----
// output phase: bucket id decoded from the staged value (no binary search)
__global__ __launch_bounds__(256) void k_scatter1(const int* __restrict__ row,
        const int* __restrict__ col, int* __restrict__ cursor,
        uint* __restrict__ bdata, int E, int chunk) {
    __shared__ uint cnt[NBK];
    __shared__ uint loc[NBK + 1];
    __shared__ uint cur[NBK];
    __shared__ uint res[NBK];
    __shared__ uint stage[S1CH];
    int tid = threadIdx.x;
    int s = blockIdx.x * chunk, e = min(E, s + chunk);
    for (int i = tid; i < NBK; i += 256) cnt[i] = 0;
    __syncthreads();
    for (int i = s + tid; i < e; i += 256) {
        int r = row[i], c = col[i];
        if (r != c) atomicAdd(&cnt[c >> RSH], 1u);
    }
    __syncthreads();
    if (tid < 64) {  // wave-0 scan of 391 counts
        uint carry = 0;
        for (int b = 0; b < NBK; b += 64) {
            int i = b + tid;
            uint v = (i < NBK) ? cnt[i] : 0;
            uint incl = v;
#pragma unroll
            for (int off = 1; off < 64; off <<= 1) {
                uint t = __shfl_up(incl, off);
                if (tid >= off) incl += t;
            }
            if (i < NBK) loc[i] = carry + incl - v;
            carry += __shfl(incl, 63);
        }
        if (tid == 0) loc[NBK] = carry;
    }
    __syncthreads();
    for (int i = tid; i < NBK; i += 256) {
        uint c = cnt[i];
        res[i] = c ? (uint)atomicAdd(&cursor[i], (int)c) : 0u;
        cur[i] = loc[i];
    }
    __syncthreads();
    for (int i = s + tid; i < e; i += 256) {
        int r = row[i], c = col[i];
        if (r != c) {
            uint slot = atomicAdd(&cur[c >> RSH], 1u);
            stage[slot] = ((uint)c << 16) | (uint)r;
        }
    }
    __syncthreads();
    uint total = loc[NBK];
    for (uint j = tid; j < total; j += 256) {
        uint v = stage[j];
        uint b = v >> (16 + RSH);           // bucket id from staged dst
        bdata[res[b] + (j - loc[b])] = v;
    }
}

// ---- pass 2: per-bucket counting sort -> padded csr + fold-in of x->fp16 staging ----
__global__ __launch_bounds__(256) void k_scatter2(const uint* __restrict__ bdata,
        const int* __restrict__ base, int* __restrict__ offs, int* __restrict__ cntout,
        unsigned short* __restrict__ csr, int N,
        const float* __restrict__ x, const float* __restrict__ dis,
        __half* __restrict__ xh, __half* __restrict__ xu, __half* __restrict__ t1h) {
    __shared__ uint cnt[RNG], locp[RNG], cur[RNG];
    __shared__ uint s_tot;
    __shared__ unsigned short srcbuf[MAXB];
    int b = blockIdx.x, tid = threadIdx.x;
    int s0 = base[b], e2 = base[b + 1];
    int m = e2 - s0;
    int sp = ((s0 + 7) & ~7) + PADB * b;   // padded, 8-aligned region start
    int dstbase = b << RSH;
    for (int i = tid; i < RNG; i += 256) cnt[i] = 0;
    __syncthreads();
    for (int i = tid; i < m; i += 256) {
        uint u = bdata[s0 + i];
        atomicAdd(&cnt[(u >> 16) & (RNG - 1)], 1u);
    }
    __syncthreads();
    if (tid < 64) {  // scan of round8(counts) in wave 0
        uint carry = 0;
        for (int r0 = 0; r0 < RNG; r0 += 64) {
            uint v = (cnt[r0 + tid] + 7u) & ~7u;
            uint incl = v;
#pragma unroll
            for (int off = 1; off < 64; off <<= 1) {
                uint t = __shfl_up(incl, off);
                if (tid >= off) incl += t;
            }
            locp[r0 + tid] = carry + incl - v;
            carry += __shfl(incl, 63);
        }
        if (tid == 0) s_tot = carry;
    }
    __syncthreads();
    uint tot = s_tot;
    if (tid < RNG) {
        int node = dstbase + tid;
        if (node < N) {
            offs[node] = sp + (int)locp[tid];
            cntout[node] = (int)((cnt[tid] + 7u) & ~7u);
        }
        cur[tid] = locp[tid];
    }
    for (uint i = tid; i < tot; i += 256) srcbuf[i] = (unsigned short)N;  // sentinel
    __syncthreads();
    for (int i = tid; i < m; i += 256) {
        uint u = bdata[s0 + i];
        uint slot = atomicAdd(&cur[(u >> 16) & (RNG - 1)], 1u);
        srcbuf[slot] = (unsigned short)(u & 0xFFFFu);
    }
    __syncthreads();
    for (uint i = tid; i < tot; i += 256) csr[sp + i] = srcbuf[i];

    // folded h2: stage this block's node range into xh (padded, dis-scaled) + xu
    for (int j = tid; j < RNG * 12; j += 256) {
        int nl = j / 12, c4 = j % 12;
        int node = dstbase + nl;
        if (node < N) {
            float d = dis[node];
            float4 v = *(const float4*)(x + (size_t)node * D + c4 * 4);
            __half2 sc0 = __floats2half2_rn(d * v.x, d * v.y);
            __half2 sc1 = __floats2half2_rn(d * v.z, d * v.w);
            uint2 so; so.x = *(uint*)&sc0; so.y = *(uint*)&sc1;
            *(uint2*)(xh + (size_t)node * DP + c4 * 4) = so;
            __half2 u0 = __floats2half2_rn(v.x, v.y);
            __half2 u1 = __floats2half2_rn(v.z, v.w);
            uint2 uo; uo.x = *(uint*)&u0; uo.y = *(uint*)&u1;
            *(uint2*)(xu + (size_t)node * D + c4 * 4) = uo;
        }
    }
    if (b == 0 && tid < 12) {  // zero sentinel rows (row N) of xh and t1h
        uint2 z = make_uint2(0u, 0u);
        *(uint2*)(xh + (size_t)N * DP + tid * 4) = z;
        *(uint2*)(t1h + (size_t)N * DP + tid * 4) = z;
    }
}

// extract 16-bit id j (0..7) from a uint4 of 8 packed u16
__device__ inline uint ext16(const uint4& p, int j) {
    uint w = (j < 4) ? ((j < 2) ? p.x : p.y) : ((j < 6) ? p.z : p.w);
    return (j & 1) ? (w >> 16) : (w & 0xFFFFu);
}

// ---- propagation: pad-8 CSR; 32/16/8-edge batches; line-aligned 128B rows ----
// wave per node; lanes 0..47: slot s=lane/12 (edge), q=lane%12 (feature quad)
// r = -alpha * dis[i] * sum_e tab[src_e] - subH(fp16)
// dstH (optional): dis[i]-scaled fp16, PADDED rows (next prop's gather table)
// dstU (optional): unscaled fp16, dense rows (k_out input / next prop's subH)
__global__ __launch_bounds__(256) void k_prop(const __half* __restrict__ tab,
        const __half* __restrict__ subH, __half* __restrict__ dstH,
        __half* __restrict__ dstU, const int* __restrict__ offs,
        const int* __restrict__ cnt, const unsigned short* __restrict__ csr,
        const float* __restrict__ dis, int n, float alpha) {
    int gw = (blockIdx.x * blockDim.x + threadIdx.x) >> 6;
    if (gw >= n) return;
    gw = __builtin_amdgcn_readfirstlane(gw);
    const int lane = threadIdx.x & 63;
    const int s = lane / 12;          // edge slot 0..3 (lanes 48..63 idle)
    const int q = lane % 12;          // halfs 4q..4q+3 of the row
    const int off = __builtin_amdgcn_readfirstlane(offs[gw]);
    const int c8 = __builtin_amdgcn_readfirstlane(cnt[gw]);  // multiple of 8
    float4 acc = make_float4(0.f, 0.f, 0.f, 0.f);
    if (lane < 48) {
        const unsigned short* cp = csr + off;   // 16B-aligned
#define GATHER8(PK)                                                         \
        {                                                                   \
            uint ia = ext16(PK, s), ib = ext16(PK, s + 4);                  \
            uint2 ga = *(const uint2*)(tab + ia * DP + q * 4);              \
            uint2 gb = *(const uint2*)(tab + ib * DP + q * 4);              \
            float2 fa0 = __half22float2(*(__half2*)&ga.x);                  \
            float2 fa1 = __half22float2(*(__half2*)&ga.y);                  \
            float2 fb0 = __half22float2(*(__half2*)&gb.x);                  \
            float2 fb1 = __half22float2(*(__half2*)&gb.y);                  \
            acc.x += fa0.x + fb0.x; acc.y += fa0.y + fb0.y;                 \
            acc.z += fa1.x + fb1.x; acc.w += fa1.y + fb1.y;                 \
        }
        int b = 0;
        for (; b + 32 <= c8; b += 32) {   // 8 gathers in flight
            uint4 p0 = *(const uint4*)(cp + b);
            uint4 p1 = *(const uint4*)(cp + b + 8);
            uint4 p2 = *(const uint4*)(cp + b + 16);
            uint4 p3 = *(const uint4*)(cp + b + 24);
            GATHER8(p0); GATHER8(p1); GATHER8(p2); GATHER8(p3);
        }
        if (b + 16 <= c8) {
            uint4 p0 = *(const uint4*)(cp + b);
            uint4 p1 = *(const uint4*)(cp + b + 8);
            GATHER8(p0); GATHER8(p1);
            b += 16;
        }
        if (b < c8) {
            uint4 p0 = *(const uint4*)(cp + b);
            GATHER8(p0);
        }
#undef GATHER8
        // reduce 4 slots (lane offsets 0,12,24,36)
        acc.x += __shfl(acc.x, lane + 24); acc.y += __shfl(acc.y, lane + 24);
        acc.z += __shfl(acc.z, lane + 24); acc.w += __shfl(acc.w, lane + 24);
        acc.x += __shfl(acc.x, lane + 12); acc.y += __shfl(acc.y, lane + 12);
        acc.z += __shfl(acc.z, lane + 12); acc.w += __shfl(acc.w, lane + 12);
        if (s == 0) {
            float dgi = dis[gw];
            float m = -alpha * dgi;
            float r0 = m * acc.x, r1 = m * acc.y, r2 = m * acc.z, r3 = m * acc.w;
            if (subH) {
                uint2 su = *(const uint2*)(subH + (size_t)gw * D + q * 4);
                float2 s0 = __half22float2(*(__half2*)&su.x);
                float2 s1 = __half22float2(*(__half2*)&su.y);
                r0 -= s0.x; r1 -= s0.y; r2 -= s1.x; r3 -= s1.y;
            }
            if (dstU) {
                __half2 o0 = __floats2half2_rn(r0, r1);
                __half2 o1 = __floats2half2_rn(r2, r3);
                uint2 o; o.x = *(uint*)&o0; o.y = *(uint*)&o1;
                *(uint2*)(dstU + (size_t)gw * D + q * 4) = o;
            }
            if (dstH) {
                __half2 o0 = __floats2half2_rn(dgi * r0, dgi * r1);
                __half2 o1 = __floats2half2_rn(dgi * r2, dgi * r3);
                uint2 o; o.x = *(uint*)&o0; o.y = *(uint*)&o1;
                *(uint2*)(dstH + (size_t)gw * DP + q * 4) = o;
            }
        }
    }
}

// ---- out = xu@W0 + t1u@W1 + t2u@W2 + t3u@W3 + bias  (all-fp16 inputs) ----
#define ONB 128
#define TLP 49
__global__ __launch_bounds__(192) void k_out(
        const __half* __restrict__ xu, const __half* __restrict__ t1u,
        const __half* __restrict__ t2u, const __half* __restrict__ t3u,
        const float* __restrict__ W, const float* __restrict__ bias,
        float* __restrict__ out, int n) {
    __shared__ float tlds[ONB * TLP];
    __shared__ float wlds[D * D];
    int tid = threadIdx.x;
    int fg = tid % 6;        // fo group: fo = fg*8 .. +7
    int ng = tid / 6;        // node group: nodes ng*4 .. +3
    int nodeBase = blockIdx.x * ONB;

    float acc[4][8];
    {
        const float4 b0 = *(const float4*)(bias + fg * 8);
        const float4 b1 = *(const float4*)(bias + fg * 8 + 4);
#pragma unroll
        for (int i = 0; i < 4; ++i) {
            acc[i][0] = b0.x; acc[i][1] = b0.y; acc[i][2] = b0.z; acc[i][3] = b0.w;
            acc[i][4] = b1.x; acc[i][5] = b1.y; acc[i][6] = b1.z; acc[i][7] = b1.w;
        }
    }

#pragma unroll
    for (int k = 0; k < KORD; ++k) {
        const __half* T = (k == 0) ? xu : (k == 1) ? t1u : (k == 2) ? t2u : t3u;
        for (int j = tid; j < D * D / 4; j += 192) {
            float4 v = *(const float4*)(W + k * D * D + j * 4);
            wlds[j * 4 + 0] = v.x; wlds[j * 4 + 1] = v.y;
            wlds[j * 4 + 2] = v.z; wlds[j * 4 + 3] = v.w;
        }
        for (int j = tid; j < ONB * 12; j += 192) {
            int nl = j / 12, c4 = j % 12;
            int node = nodeBase + nl;
            float4 v = make_float4(0.f, 0.f, 0.f, 0.f);
            if (node < n) {
                uint2 u = *(const uint2*)(T + (size_t)node * D + c4 * 4);
                float2 a = __half22float2(*(__half2*)&u.x);
                float2 b = __half22float2(*(__half2*)&u.y);
                v = make_float4(a.x, a.y, b.x, b.y);
            }
            float* pp = tlds + nl * TLP + c4 * 4;
            pp[0] = v.x; pp[1] = v.y; pp[2] = v.z; pp[3] = v.w;
        }
        __syncthreads();
#pragma unroll 4
        for (int f = 0; f < D; ++f) {
            const float4 w0 = *(const float4*)(wlds + f * D + fg * 8);
            const float4 w1 = *(const float4*)(wlds + f * D + fg * 8 + 4);
            float tv[4];
#pragma unroll
            for (int i = 0; i < 4; ++i) tv[i] = tlds[(ng * 4 + i) * TLP + f];
#pragma unroll
            for (int i = 0; i < 4; ++i) {
                acc[i][0] += tv[i] * w0.x; acc[i][1] += tv[i] * w0.y;
                acc[i][2] += tv[i] * w0.z; acc[i][3] += tv[i] * w0.w;
                acc[i][4] += tv[i] * w1.x; acc[i][5] += tv[i] * w1.y;
                acc[i][6] += tv[i] * w1.z; acc[i][7] += tv[i] * w1.w;
            }
        }
        __syncthreads();
    }

#pragma unroll
    for (int i = 0; i < 4; ++i) {
        int node = nodeBase + ng * 4 + i;
        if (node < n) {
            float4 o0 = make_float4(acc[i][0], acc[i][1], acc[i][2], acc[i][3]);
            float4 o1 = make_float4(acc[i][4], acc[i][5], acc[i][6], acc[i][7]);
            *(float4*)(out + node * D + fg * 8) = o0;
            *(float4*)(out + node * D + fg * 8 + 4) = o1;
        }
    }
}

extern "C" void kernel_launch(void* const* d_in, const int* in_sizes, int n_in,
                              void* d_out, int out_size, void* d_ws, size_t ws_size,
                              hipStream_t stream) {
    const float* x    = (const float*)d_in[0];
    const int*   ei   = (const int*)d_in[1];
    const float* W    = (const float*)d_in[2];
    const float* bias = (const float*)d_in[3];
    float* out = (float*)d_out;

    int n = in_sizes[0] / D;   // 50000
    int E = in_sizes[1] / 2;   // 1.6M
    const int* row  = ei;      // source j
    const int* colp = ei + E;  // target i

    char* ws = (char*)d_ws;
    // region A: bdata (scatter1->scatter2) -> xh (scatter2->prop1 gather) -> t2h
    // (t2h inherits xh's zeroed sentinel row: same pointer, same padded layout)
    size_t Abytes = (size_t)E * 4;
    size_t xhBytes = (size_t)(n + 1) * DP * 2;   // padded rows + sentinel
    if (xhBytes > Abytes) Abytes = xhBytes;
    Abytes = (Abytes + 255) & ~(size_t)255;
    char* Aptr = ws; ws += Abytes;
    uint*   bdata = (uint*)Aptr;
    __half* xh    = (__half*)Aptr;
    __half* t2h   = (__half*)Aptr;
    uint* coarse  = (uint*)ws; ws += (size_t)NBK * 4;
    int*  basep   = (int*)ws;  ws += (size_t)(NBK + 1) * 4;
    int*  cursor  = (int*)ws;  ws += (size_t)NBK * 4;
    ws = (char*)(((size_t)ws + 255) & ~(size_t)255);
    float* dis    = (float*)ws; ws += (size_t)n * 4;
    int*   offs   = (int*)ws;   ws += (size_t)n * 4;
    int*   cntout = (int*)ws;   ws += (size_t)n * 4;
    int CSRN = E + NBK * PADB + 64;  // padded CSR capacity
    unsigned short* csr = (unsigned short*)ws; ws += ((size_t)CSRN * 2 + 255) & ~(size_t)255;
    // region B: histbuf (hist->reduce, 6.4MB) -> xu + t1u (dense fp16, 9.6MB)
    size_t Bbytes = (size_t)HB * 2 * HW * 4;
    size_t uBytes = (size_t)n * D * 2 * 2;      // xu + t1u
    if (uBytes > Bbytes) Bbytes = uBytes;
    char* Bptr = ws; ws += (Bbytes + 255) & ~(size_t)255;
    uint*   histbuf = (uint*)Bptr;
    __half* xu      = (__half*)Bptr;
    __half* t1u     = (__half*)(Bptr + (size_t)n * D * 2);
    __half* t1h     = (__half*)ws; ws += ((size_t)(n + 1) * DP * 2 + 255) & ~(size_t)255;
    __half* t2u     = (__half*)ws; ws += (size_t)n * D * 2;
    __half* t3u     = (__half*)ws; ws += (size_t)n * D * 2;

    hipMemsetAsync(coarse, 0, (size_t)NBK * 4, stream);

    int chunkH = (E + HB - 1) / HB;
    k_hist<<<2 * HB, 1024, 0, stream>>>(row, colp, histbuf, coarse, E, chunkH);
    k_reduce<<<(n / 2 + 255) / 256, 256, 0, stream>>>(histbuf, dis, n / 2,
                                                      coarse, basep, cursor, NBK);
    int chunk1 = (E + 255) / 256;
    k_scatter1<<<256, 256, 0, stream>>>(row, colp, cursor, bdata, E, chunk1);
    k_scatter2<<<NBK, 256, 0, stream>>>(bdata, basep, offs, cntout, csr, n,
                                        x, dis, xh, xu, t1h);

    int pblocks = (n + 3) / 4;  // 4 waves (=4 nodes) per 256-thread block
    // t1 = P(x):           t1h scaled (padded gather), t1u unscaled (dense)
    k_prop<<<pblocks, 256, 0, stream>>>(xh,  nullptr, t1h, t1u, offs, cntout, csr, dis, n, 1.0f);
    // t2 = 2 P(t1) - x:    t2h scaled (padded gather), t2u unscaled (dense)
    k_prop<<<pblocks, 256, 0, stream>>>(t1h, xu,      t2h, t2u, offs, cntout, csr, dis, n, 2.0f);
    // t3 = 2 P(t2) - t1:   t3u unscaled only
    k_prop<<<pblocks, 256, 0, stream>>>(t2h, t1u, nullptr, t3u, offs, cntout, csr, dis, n, 2.0f);

    k_out<<<(n + ONB - 1) / ONB, 192, 0, stream>>>(xu, t1u, t2u, t3u, W, bias, out, n);
}

// Round 15
// 169.124 us; speedup vs baseline: 1.0372x; 1.0372x over previous
//
#include <hip/hip_runtime.h>
#include <hip/hip_fp16.h>

#define D 48
#define KORD 4
#define RSH 7             // 128 dst ids per bucket
#define RNG 128
#define NBK 391           // ceil(50000/128)
#define HB 64             // histogram chunks
#define HHALF 25000       // node ids per half
#define HW 12500          // packed words per half
#define S1CH 6272         // pass-1 chunk capacity (>= ceil(E/256))
#define MAXB 6144         // max PADDED entries per bucket
#define PADB 960          // per-bucket slack for 8-rounding (multiple of 8)

// ---- outdeg histogram (privatized, no global atomics) + coarse bucket hist ----
__global__ __launch_bounds__(1024) void k_hist(const int* __restrict__ row,
        const int* __restrict__ col, uint* __restrict__ histbuf,
        uint* __restrict__ coarse, int E, int chunk) {
    __shared__ uint hist[HW];     // 50 KB: packed ushort counters for one id-half
    __shared__ uint ch[NBK];
    int k = blockIdx.x >> 1, h = blockIdx.x & 1;
    int tid = threadIdx.x;
    for (int i = tid; i < HW; i += 1024) hist[i] = 0;
    if (h == 0) for (int i = tid; i < NBK; i += 1024) ch[i] = 0;
    __syncthreads();
    int lo = h * HHALF;
    int s = k * chunk, e = min(E, s + chunk);
    for (int i = s + tid; i < e; i += 1024) {
        int r = row[i], c = col[i];
        if (r != c) {
            unsigned rl = (unsigned)(r - lo);
            if (rl < HHALF) atomicAdd(&hist[rl >> 1], 1u << ((rl & 1) * 16));
            if (h == 0) atomicAdd(&ch[c >> RSH], 1u);
        }
    }
    __syncthreads();
    uint* dst = histbuf + (size_t)k * (2 * HW) + (size_t)h * HW;
    for (int i = tid; i < HW; i += 1024) dst[i] = hist[i];
    if (h == 0) for (int i = tid; i < NBK; i += 1024) atomicAdd(&coarse[i], ch[i]);
}

// ---- reduce private histograms -> dis = deg^{-1/2}; block 0 also scans coarse ----
__global__ void k_reduce(const uint* __restrict__ histbuf, float* __restrict__ dis,
                         int nwords, const uint* __restrict__ coarse,
                         int* __restrict__ base, int* __restrict__ cursor, int nbk) {
    int t = blockIdx.x * blockDim.x + threadIdx.x;  // word t = nodes 2t,2t+1
    if (t < nwords) {
        uint lo = 0, hi = 0;
#pragma unroll 8
        for (int k = 0; k < HB; ++k) {
            uint w = histbuf[(size_t)k * (2 * HW) + t];
            lo += w & 0xFFFFu;
            hi += w >> 16;
        }
        float2 d;
        d.x = lo ? rsqrtf((float)lo) : 0.0f;
        d.y = hi ? rsqrtf((float)hi) : 0.0f;
        *(float2*)(dis + 2 * t) = d;
    }
    // fold-in of the coarse-bucket exclusive scan (independent data)
    if (blockIdx.x == 0 && threadIdx.x < 64) {
        int lane = threadIdx.x;
        int carry = 0;
        for (int s = 0; s < nbk; s += 64) {
            int i = s + lane;
            int v = (i < nbk) ? (int)coarse[i] : 0;
            int incl = v;
#pragma unroll
            for (int off = 1; off < 64; off <<= 1) {
                int tt = __shfl_up(incl, off);
                if (lane >= off) incl += tt;
            }
            if (i < nbk) { int ex = carry + incl - v; base[i] = ex; cursor[i] = ex; }
            carry += __shfl(incl, 63);
        }
        if (lane == 0) base[nbk] = carry;
    }
}

// ---- pass 1: scatter edges into coarse buckets, coalesced run writes ----
// output phase: bucket id decoded from the staged value (no binary search)
__global__ __launch_bounds__(256) void k_scatter1(const int* __restrict__ row,
        const int* __restrict__ col, int* __restrict__ cursor,
        uint* __restrict__ bdata, int E, int chunk) {
    __shared__ uint cnt[NBK];
    __shared__ uint loc[NBK + 1];
    __shared__ uint cur[NBK];
    __shared__ uint res[NBK];
    __shared__ uint stage[S1CH];
    int tid = threadIdx.x;
    int s = blockIdx.x * chunk, e = min(E, s + chunk);
    for (int i = tid; i < NBK; i += 256) cnt[i] = 0;
    __syncthreads();
    for (int i = s + tid; i < e; i += 256) {
        int r = row[i], c = col[i];
        if (r != c) atomicAdd(&cnt[c >> RSH], 1u);
    }
    __syncthreads();
    if (tid < 64) {  // wave-0 scan of 391 counts
        uint carry = 0;
        for (int b = 0; b < NBK; b += 64) {
            int i = b + tid;
            uint v = (i < NBK) ? cnt[i] : 0;
            uint incl = v;
#pragma unroll
            for (int off = 1; off < 64; off <<= 1) {
                uint t = __shfl_up(incl, off);
                if (tid >= off) incl += t;
            }
            if (i < NBK) loc[i] = carry + incl - v;
            carry += __shfl(incl, 63);
        }
        if (tid == 0) loc[NBK] = carry;
    }
    __syncthreads();
    for (int i = tid; i < NBK; i += 256) {
        uint c = cnt[i];
        res[i] = c ? (uint)atomicAdd(&cursor[i], (int)c) : 0u;
        cur[i] = loc[i];
    }
    __syncthreads();
    for (int i = s + tid; i < e; i += 256) {
        int r = row[i], c = col[i];
        if (r != c) {
            uint slot = atomicAdd(&cur[c >> RSH], 1u);
            stage[slot] = ((uint)c << 16) | (uint)r;
        }
    }
    __syncthreads();
    uint total = loc[NBK];
    for (uint j = tid; j < total; j += 256) {
        uint v = stage[j];
        uint b = v >> (16 + RSH);           // bucket id from staged dst
        bdata[res[b] + (j - loc[b])] = v;
    }
}

// ---- pass 2: per-bucket counting sort -> padded csr + folded x->fp16 staging ----
// xh lives OUTSIDE bdata's region (no cross-block alias with bdata reads)
__global__ __launch_bounds__(256) void k_scatter2(const uint* __restrict__ bdata,
        const int* __restrict__ base, int* __restrict__ offs, int* __restrict__ cntout,
        unsigned short* __restrict__ csr, int N,
        const float* __restrict__ x, const float* __restrict__ dis,
        __half* __restrict__ xh, __half* __restrict__ xu, __half* __restrict__ t1h) {
    __shared__ uint cnt[RNG], locp[RNG], cur[RNG];
    __shared__ uint s_tot;
    __shared__ unsigned short srcbuf[MAXB];
    int b = blockIdx.x, tid = threadIdx.x;
    int s0 = base[b], e2 = base[b + 1];
    int m = e2 - s0;
    int sp = ((s0 + 7) & ~7) + PADB * b;   // padded, 8-aligned region start
    int dstbase = b << RSH;
    for (int i = tid; i < RNG; i += 256) cnt[i] = 0;
    __syncthreads();
    for (int i = tid; i < m; i += 256) {
        uint u = bdata[s0 + i];
        atomicAdd(&cnt[(u >> 16) & (RNG - 1)], 1u);
    }
    __syncthreads();
    if (tid < 64) {  // scan of round8(counts) in wave 0
        uint carry = 0;
        for (int r0 = 0; r0 < RNG; r0 += 64) {
            uint v = (cnt[r0 + tid] + 7u) & ~7u;
            uint incl = v;
#pragma unroll
            for (int off = 1; off < 64; off <<= 1) {
                uint t = __shfl_up(incl, off);
                if (tid >= off) incl += t;
            }
            locp[r0 + tid] = carry + incl - v;
            carry += __shfl(incl, 63);
        }
        if (tid == 0) s_tot = carry;
    }
    __syncthreads();
    uint tot = s_tot;
    if (tid < RNG) {
        int node = dstbase + tid;
        if (node < N) {
            offs[node] = sp + (int)locp[tid];
            cntout[node] = (int)((cnt[tid] + 7u) & ~7u);
        }
        cur[tid] = locp[tid];
    }
    for (uint i = tid; i < tot; i += 256) srcbuf[i] = (unsigned short)N;  // sentinel
    __syncthreads();
    for (int i = tid; i < m; i += 256) {
        uint u = bdata[s0 + i];
        uint slot = atomicAdd(&cur[(u >> 16) & (RNG - 1)], 1u);
        srcbuf[slot] = (unsigned short)(u & 0xFFFFu);
    }
    __syncthreads();
    for (uint i = tid; i < tot; i += 256) csr[sp + i] = srcbuf[i];

    // folded h2: stage this block's node range into xh (dis-scaled) + xu (unscaled)
    for (int j = tid; j < RNG * 12; j += 256) {
        int nl = j / 12, c4 = j % 12;
        int node = dstbase + nl;
        if (node < N) {
            float d = dis[node];
            float4 v = *(const float4*)(x + (size_t)node * D + c4 * 4);
            __half2 sc0 = __floats2half2_rn(d * v.x, d * v.y);
            __half2 sc1 = __floats2half2_rn(d * v.z, d * v.w);
            uint2 so; so.x = *(uint*)&sc0; so.y = *(uint*)&sc1;
            *(uint2*)(xh + (size_t)node * D + c4 * 4) = so;
            __half2 u0 = __floats2half2_rn(v.x, v.y);
            __half2 u1 = __floats2half2_rn(v.z, v.w);
            uint2 uo; uo.x = *(uint*)&u0; uo.y = *(uint*)&u1;
            *(uint2*)(xu + (size_t)node * D + c4 * 4) = uo;
        }
    }
    if (b == 0 && tid < 12) {  // zero sentinel rows (row N) of xh and t1h
        uint2 z = make_uint2(0u, 0u);
        *(uint2*)(xh + (size_t)N * D + tid * 4) = z;
        *(uint2*)(t1h + (size_t)N * D + tid * 4) = z;
    }
}

// extract 16-bit id j (0..7) from a uint4 of 8 packed u16
__device__ inline uint ext16(const uint4& p, int j) {
    uint w = (j < 4) ? ((j < 2) ? p.x : p.y) : ((j < 6) ? p.z : p.w);
    return (j & 1) ? (w >> 16) : (w & 0xFFFFu);
}

// ---- propagation (R8 gather shape): pad-8 CSR; 32/16/8-edge batches ----
// wave per node; lanes 0..47: slot s=lane/12 (edge), q=lane%12 (feature quad)
// r = -alpha * dis[i] * sum_e tab[src_e] - subH(fp16)
// dstH (optional): dis[i]-scaled fp16 (next prop's gather table)
// dstU (optional): unscaled fp16 (k_out input / next prop's subH)
// sentZero: node-0 wave also zeroes dstH's sentinel row N (needed when dstH
// aliases a buffer whose row N held garbage, e.g. t2h over dead bdata)
__global__ __launch_bounds__(256) void k_prop(const __half* __restrict__ tab,
        const __half* __restrict__ subH, __half* __restrict__ dstH,
        __half* __restrict__ dstU, const int* __restrict__ offs,
        const int* __restrict__ cnt, const unsigned short* __restrict__ csr,
        const float* __restrict__ dis, int n, float alpha, int sentZero) {
    int gw = (blockIdx.x * blockDim.x + threadIdx.x) >> 6;
    if (gw >= n) return;
    gw = __builtin_amdgcn_readfirstlane(gw);
    const int lane = threadIdx.x & 63;
    const int s = lane / 12;          // edge slot 0..3 (lanes 48..63 idle)
    const int q = lane % 12;          // halfs 4q..4q+3 of the row
    const int off = __builtin_amdgcn_readfirstlane(offs[gw]);
    const int c8 = __builtin_amdgcn_readfirstlane(cnt[gw]);  // multiple of 8
    float4 acc = make_float4(0.f, 0.f, 0.f, 0.f);
    if (lane < 48) {
        const unsigned short* cp = csr + off;   // 16B-aligned
#define GATHER8(PK)                                                         \
        {                                                                   \
            uint ia = ext16(PK, s), ib = ext16(PK, s + 4);                  \
            uint2 ga = *(const uint2*)(tab + ia * D + q * 4);               \
            uint2 gb = *(const uint2*)(tab + ib * D + q * 4);               \
            float2 fa0 = __half22float2(*(__half2*)&ga.x);                  \
            float2 fa1 = __half22float2(*(__half2*)&ga.y);                  \
            float2 fb0 = __half22float2(*(__half2*)&gb.x);                  \
            float2 fb1 = __half22float2(*(__half2*)&gb.y);                  \
            acc.x += fa0.x + fb0.x; acc.y += fa0.y + fb0.y;                 \
            acc.z += fa1.x + fb1.x; acc.w += fa1.y + fb1.y;                 \
        }
        int b = 0;
        for (; b + 32 <= c8; b += 32) {   // 8 gathers in flight
            uint4 p0 = *(const uint4*)(cp + b);
            uint4 p1 = *(const uint4*)(cp + b + 8);
            uint4 p2 = *(const uint4*)(cp + b + 16);
            uint4 p3 = *(const uint4*)(cp + b + 24);
            GATHER8(p0); GATHER8(p1); GATHER8(p2); GATHER8(p3);
        }
        if (b + 16 <= c8) {
            uint4 p0 = *(const uint4*)(cp + b);
            uint4 p1 = *(const uint4*)(cp + b + 8);
            GATHER8(p0); GATHER8(p1);
            b += 16;
        }
        if (b < c8) {
            uint4 p0 = *(const uint4*)(cp + b);
            GATHER8(p0);
        }
#undef GATHER8
        // reduce 4 slots (lane offsets 0,12,24,36)
        acc.x += __shfl(acc.x, lane + 24); acc.y += __shfl(acc.y, lane + 24);
        acc.z += __shfl(acc.z, lane + 24); acc.w += __shfl(acc.w, lane + 24);
        acc.x += __shfl(acc.x, lane + 12); acc.y += __shfl(acc.y, lane + 12);
        acc.z += __shfl(acc.z, lane + 12); acc.w += __shfl(acc.w, lane + 12);
        if (s == 0) {
            float dgi = dis[gw];
            float m = -alpha * dgi;
            float r0 = m * acc.x, r1 = m * acc.y, r2 = m * acc.z, r3 = m * acc.w;
            if (subH) {
                uint2 su = *(const uint2*)(subH + (size_t)gw * D + q * 4);
                float2 s0 = __half22float2(*(__half2*)&su.x);
                float2 s1 = __half22float2(*(__half2*)&su.y);
                r0 -= s0.x; r1 -= s0.y; r2 -= s1.x; r3 -= s1.y;
            }
            if (dstU) {
                __half2 o0 = __floats2half2_rn(r0, r1);
                __half2 o1 = __floats2half2_rn(r2, r3);
                uint2 o; o.x = *(uint*)&o0; o.y = *(uint*)&o1;
                *(uint2*)(dstU + (size_t)gw * D + q * 4) = o;
            }
            if (dstH) {
                __half2 o0 = __floats2half2_rn(dgi * r0, dgi * r1);
                __half2 o1 = __floats2half2_rn(dgi * r2, dgi * r3);
                uint2 o; o.x = *(uint*)&o0; o.y = *(uint*)&o1;
                *(uint2*)(dstH + (size_t)gw * D + q * 4) = o;
                if (sentZero && gw == 0) {  // fix: zero dstH sentinel row N
                    uint2 z = make_uint2(0u, 0u);
                    *(uint2*)(dstH + (size_t)n * D + q * 4) = z;
                }
            }
        }
    }
}

// ---- out = xu@W0 + t1u@W1 + t2u@W2 + t3u@W3 + bias  (all-fp16 inputs) ----
#define ONB 128
#define TLP 49
__global__ __launch_bounds__(192) void k_out(
        const __half* __restrict__ xu, const __half* __restrict__ t1u,
        const __half* __restrict__ t2u, const __half* __restrict__ t3u,
        const float* __restrict__ W, const float* __restrict__ bias,
        float* __restrict__ out, int n) {
    __shared__ float tlds[ONB * TLP];
    __shared__ float wlds[D * D];
    int tid = threadIdx.x;
    int fg = tid % 6;        // fo group: fo = fg*8 .. +7
    int ng = tid / 6;        // node group: nodes ng*4 .. +3
    int nodeBase = blockIdx.x * ONB;

    float acc[4][8];
    {
        const float4 b0 = *(const float4*)(bias + fg * 8);
        const float4 b1 = *(const float4*)(bias + fg * 8 + 4);
#pragma unroll
        for (int i = 0; i < 4; ++i) {
            acc[i][0] = b0.x; acc[i][1] = b0.y; acc[i][2] = b0.z; acc[i][3] = b0.w;
            acc[i][4] = b1.x; acc[i][5] = b1.y; acc[i][6] = b1.z; acc[i][7] = b1.w;
        }
    }

#pragma unroll
    for (int k = 0; k < KORD; ++k) {
        const __half* T = (k == 0) ? xu : (k == 1) ? t1u : (k == 2) ? t2u : t3u;
        for (int j = tid; j < D * D / 4; j += 192) {
            float4 v = *(const float4*)(W + k * D * D + j * 4);
            wlds[j * 4 + 0] = v.x; wlds[j * 4 + 1] = v.y;
            wlds[j * 4 + 2] = v.z; wlds[j * 4 + 3] = v.w;
        }
        for (int j = tid; j < ONB * 12; j += 192) {
            int nl = j / 12, c4 = j % 12;
            int node = nodeBase + nl;
            float4 v = make_float4(0.f, 0.f, 0.f, 0.f);
            if (node < n) {
                uint2 u = *(const uint2*)(T + (size_t)node * D + c4 * 4);
                float2 a = __half22float2(*(__half2*)&u.x);
                float2 b = __half22float2(*(__half2*)&u.y);
                v = make_float4(a.x, a.y, b.x, b.y);
            }
            float* pp = tlds + nl * TLP + c4 * 4;
            pp[0] = v.x; pp[1] = v.y; pp[2] = v.z; pp[3] = v.w;
        }
        __syncthreads();
#pragma unroll 4
        for (int f = 0; f < D; ++f) {
            const float4 w0 = *(const float4*)(wlds + f * D + fg * 8);
            const float4 w1 = *(const float4*)(wlds + f * D + fg * 8 + 4);
            float tv[4];
#pragma unroll
            for (int i = 0; i < 4; ++i) tv[i] = tlds[(ng * 4 + i) * TLP + f];
#pragma unroll
            for (int i = 0; i < 4; ++i) {
                acc[i][0] += tv[i] * w0.x; acc[i][1] += tv[i] * w0.y;
                acc[i][2] += tv[i] * w0.z; acc[i][3] += tv[i] * w0.w;
                acc[i][4] += tv[i] * w1.x; acc[i][5] += tv[i] * w1.y;
                acc[i][6] += tv[i] * w1.z; acc[i][7] += tv[i] * w1.w;
            }
        }
        __syncthreads();
    }

#pragma unroll
    for (int i = 0; i < 4; ++i) {
        int node = nodeBase + ng * 4 + i;
        if (node < n) {
            float4 o0 = make_float4(acc[i][0], acc[i][1], acc[i][2], acc[i][3]);
            float4 o1 = make_float4(acc[i][4], acc[i][5], acc[i][6], acc[i][7]);
            *(float4*)(out + node * D + fg * 8) = o0;
            *(float4*)(out + node * D + fg * 8 + 4) = o1;
        }
    }
}

extern "C" void kernel_launch(void* const* d_in, const int* in_sizes, int n_in,
                              void* d_out, int out_size, void* d_ws, size_t ws_size,
                              hipStream_t stream) {
    const float* x    = (const float*)d_in[0];
    const int*   ei   = (const int*)d_in[1];
    const float* W    = (const float*)d_in[2];
    const float* bias = (const float*)d_in[3];
    float* out = (float*)d_out;

    int n = in_sizes[0] / D;   // 50000
    int E = in_sizes[1] / 2;   // 1.6M
    const int* row  = ei;      // source j
    const int* colp = ei + E;  // target i

    char* ws = (char*)d_ws;
    // region A: bdata (scatter1->scatter2) -> t2h (prop2->prop3). xh is SEPARATE
    // (folded h2 in scatter2 writes xh while other blocks still read bdata).
    // t2h's sentinel row is zeroed by prop2 (sentZero=1) since bdata left garbage.
    size_t Abytes = (size_t)E * 4;
    size_t t2hBytes = (size_t)(n + 1) * D * 2;
    if (t2hBytes > Abytes) Abytes = t2hBytes;
    Abytes = (Abytes + 255) & ~(size_t)255;
    char* Aptr = ws; ws += Abytes;
    uint*   bdata = (uint*)Aptr;
    __half* t2h   = (__half*)Aptr;     // prop2 writes AFTER bdata is dead
    uint* coarse  = (uint*)ws; ws += (size_t)NBK * 4;
    int*  basep   = (int*)ws;  ws += (size_t)(NBK + 1) * 4;
    int*  cursor  = (int*)ws;  ws += (size_t)NBK * 4;
    ws = (char*)(((size_t)ws + 255) & ~(size_t)255);
    float* dis    = (float*)ws; ws += (size_t)n * 4;
    int*   offs   = (int*)ws;   ws += (size_t)n * 4;
    int*   cntout = (int*)ws;   ws += (size_t)n * 4;
    int CSRN = E + NBK * PADB + 64;  // padded CSR capacity
    unsigned short* csr = (unsigned short*)ws; ws += ((size_t)CSRN * 2 + 255) & ~(size_t)255;
    // region B: histbuf (hist->reduce, 6.4MB) -> xu + t1u (dense fp16, 9.6MB)
    size_t Bbytes = (size_t)HB * 2 * HW * 4;
    size_t uBytes = (size_t)n * D * 2 * 2;      // xu + t1u
    if (uBytes > Bbytes) Bbytes = uBytes;
    char* Bptr = ws; ws += (Bbytes + 255) & ~(size_t)255;
    uint*   histbuf = (uint*)Bptr;
    __half* xu      = (__half*)Bptr;
    __half* t1u     = (__half*)(Bptr + (size_t)n * D * 2);
    __half* xh      = (__half*)ws; ws += ((size_t)(n + 1) * D * 2 + 255) & ~(size_t)255;
    __half* t1h     = (__half*)ws; ws += ((size_t)(n + 1) * D * 2 + 255) & ~(size_t)255;
    __half* t2u     = (__half*)ws; ws += (size_t)n * D * 2;
    __half* t3u     = (__half*)ws; ws += (size_t)n * D * 2;

    hipMemsetAsync(coarse, 0, (size_t)NBK * 4, stream);

    int chunkH = (E + HB - 1) / HB;
    k_hist<<<2 * HB, 1024, 0, stream>>>(row, colp, histbuf, coarse, E, chunkH);
    k_reduce<<<(n / 2 + 255) / 256, 256, 0, stream>>>(histbuf, dis, n / 2,
                                                      coarse, basep, cursor, NBK);
    int chunk1 = (E + 255) / 256;
    k_scatter1<<<256, 256, 0, stream>>>(row, colp, cursor, bdata, E, chunk1);
    k_scatter2<<<NBK, 256, 0, stream>>>(bdata, basep, offs, cntout, csr, n,
                                        x, dis, xh, xu, t1h);

    int pblocks = (n + 3) / 4;  // 4 waves (=4 nodes) per 256-thread block
    // t1 = P(x):           t1h scaled (gather), t1u unscaled
    k_prop<<<pblocks, 256, 0, stream>>>(xh,  nullptr, t1h, t1u, offs, cntout, csr, dis, n, 1.0f, 0);
    // t2 = 2 P(t1) - x:    t2h scaled (gather; sentinel zeroed here), t2u unscaled
    k_prop<<<pblocks, 256, 0, stream>>>(t1h, xu,      t2h, t2u, offs, cntout, csr, dis, n, 2.0f, 1);
    // t3 = 2 P(t2) - t1:   t3u unscaled only
    k_prop<<<pblocks, 256, 0, stream>>>(t2h, t1u, nullptr, t3u, offs, cntout, csr, dis, n, 2.0f, 0);

    k_out<<<(n + ONB - 1) / ONB, 192, 0, stream>>>(xu, t1u, t2u, t3u, W, bias, out, n);
}